// Round 12
// baseline (415.450 us; speedup 1.0000x reference)
//
#include <hip/hip_runtime.h>
#include <math.h>

// ---- geometry constants (match reference) ----
#define NA   24
#define NU   128
#define NV   64
#define NW   128   // volume W (x)
#define NH   128   // volume H (y)
#define ND   64    // volume D (z)
#define NS   128   // samples per ray
#define F_STEP 1.5625f            // 2*HS/S = 200/128
#define F_DL  (200.0f / 127.0f)   // linspace(156,356,128) spacing
#define F_L0  156.0f
#define INV_DL (127.0f / 200.0f)

#define NRAYS (NA * NV * NU)      // 196608
#define VOX   (NW * NH * ND)      // 1048576
#define NSEG  4                   // part slices (2 half-segments each)
#define NHSEG 8                   // fp half-segments of 16 samples

// padded volume: planes {guard, padz(-1), z0..z63, padz(64), guard} x 130 x 130
#define PPX  130
#define PPY  130
#define PPZ  68
#define PPLANE (PPX * PPY)        // 16900
#define PVN  (PPZ * PPLANE)       // 1,149,200
#define CBASE (2 * PPLANE + PPX + 1)   // voxel(0,0,0) linear offset

typedef float v2f __attribute__((ext_vector_type(2)));
// 8-byte vector load with only 4-byte alignment guarantee (per-lane x-pair).
typedef float f2v __attribute__((ext_vector_type(2)));
typedef f2v __attribute__((aligned(4))) f2u;

// cos/sin(k*15 deg)
__device__ __constant__ float CSA[NA] = {
    1.0f,  0.96592582628906829f,  0.86602540378443865f,  0.70710678118654752f,
    0.5f,  0.25881904510252076f,  0.0f,                 -0.25881904510252076f,
   -0.5f, -0.70710678118654752f, -0.86602540378443865f, -0.96592582628906829f,
   -1.0f, -0.96592582628906829f, -0.86602540378443865f, -0.70710678118654752f,
   -0.5f, -0.25881904510252076f,  0.0f,                  0.25881904510252076f,
    0.5f,  0.70710678118654752f,  0.86602540378443865f,  0.96592582628906829f
};
__device__ __constant__ float SNA[NA] = {
    0.0f,  0.25881904510252076f,  0.5f,                  0.70710678118654752f,
    0.86602540378443865f,  0.96592582628906829f,  1.0f,  0.96592582628906829f,
    0.86602540378443865f,  0.70710678118654752f,  0.5f,  0.25881904510252076f,
    0.0f, -0.25881904510252076f, -0.5f,                 -0.70710678118654752f,
   -0.86602540378443865f, -0.96592582628906829f, -1.0f, -0.96592582628906829f,
   -0.86602540378443865f, -0.70710678118654752f, -0.5f, -0.25881904510252076f
};

// ---------------- volume padding + out/part zero-init ----------------
// Zeroes `out` (bp accumulates via global atomicAdd) and `part` (fp now
// accumulates two half-segments per slice via atomicAdd). Piggybacked here:
// no memset API inside graph capture; stream order guarantees visibility.
__global__ __launch_bounds__(256) void pad_kernel(const float* __restrict__ vol,
                                                  float* __restrict__ padv,
                                                  float* __restrict__ outz,
                                                  float* __restrict__ partz) {
    int i = blockIdx.x * 256 + threadIdx.x;
    if (i >= PVN) return;
    if (i < VOX) outz[i] = 0.0f;
    if (i < NSEG * NRAYS) partz[i] = 0.0f;
    int x = i % PPX;
    int t = i / PPX;
    int y = t % PPY;
    int z = t / PPY;
    float val = 0.0f;
    if (z >= 2 && z <= 65 && y >= 1 && y <= 128 && x >= 1 && x <= 128)
        val = vol[(((z - 2) << 7) + (y - 1) << 7) + (x - 1)];
    padv[i] = val;
}

// Per-ray geometry for FP.
__device__ __forceinline__ void ray_setup(int a, int v, int u,
                                          float& sx, float& sy,
                                          float& dx, float& dy, float& dz) {
    float ang = (float)((double)a * (15.0 * M_PI / 180.0));
    float c = cosf(ang), s = sinf(ang);
    float uu = (float)u - 63.5f;
    float vv = (float)v - 31.5f;
    float ux = 512.0f * c - uu * s;
    float uy = 512.0f * s + uu * c;
    float uz = vv;
    float invn = 1.0f / sqrtf(ux * ux + uy * uy + uz * uz);
    dx = ux * invn; dy = uy * invn; dz = uz * invn;
    sx = -256.0f * c; sy = -256.0f * s;
}

// ---------------- forward projection: 8 half-segments, 128-thread blocks ----------------
// R27: apply the session's one CONFIRMED mechanism (generation-quantization,
// bp R9: -8%) to fp. Old fp: 3072 blocks of 256 threads, <=32-sample quantum
// -> ~1.5-3 ragged generations. New: 12288 blocks of 128 threads (one full
// u-row each; 2-wave scheduling granularity; 16 blk/CU x 2 waves still allows
// 32 waves/CU), 8 half-segments of 16 samples. Two half-segments share a part
// slice via atomicAdd (2 contributions/element; part zeroed in pad; sum-order
// perturbation only -- same class as R9's out-atomics). Setup recompute
// doubles (~+1us chip-wide). Body = R23/R25 form (pair loads; prefetch
// scaffolding dropped -- R26 proved it null).
__global__ __launch_bounds__(128) void fp_seg_kernel(const float* __restrict__ padv,
                                                     float* __restrict__ part) {
    int r = blockIdx.x * 128 + threadIdx.x;
    int hs = blockIdx.y;              // half-segment 0..7 (16 samples each)
    int u = r & (NU - 1);
    int v = (r >> 7) & (NV - 1);
    int a = r >> 13;

    float sx, sy, dx, dy, dz;
    ray_setup(a, v, u, sx, sy, dx, dy, dz);

    // exact-support window (voxel weights are zero outside +-64.5 / +-32.5)
    float rx = 1.0f / dx, ry = 1.0f / dy, rz = 1.0f / dz;
    float ex0 = (-64.51f - sx) * rx, ex1 = (64.51f - sx) * rx;
    float ey0 = (-64.51f - sy) * ry, ey1 = (64.51f - sy) * ry;
    float ez0 = (-32.51f) * rz,      ez1 = (32.51f) * rz;
    float llo = fmaxf(fmaxf(fminf(ex0, ex1), fminf(ey0, ey1)), fminf(ez0, ez1));
    float lhi = fminf(fminf(fmaxf(ex0, ex1), fmaxf(ey0, ey1)), fmaxf(ez0, ez1));
    int i_lo = max(hs * 16,      (int)ceilf((llo - F_L0) * INV_DL));
    int i_hi = min(hs * 16 + 15, (int)floorf((lhi - F_L0) * INV_DL));

    float acc = 0.0f;
    for (int i = i_lo; i <= i_hi; ++i) {
        float ell = fmaf((float)i, F_DL, F_L0);
        float cx = fmaf(ell, dx, sx) + 63.5f;   // voxel-index space
        float cy = fmaf(ell, dy, sy) + 63.5f;
        float cz = ell * dz + 31.5f;
        float fx = floorf(cx), fy = floorf(cy), fz = floorf(cz);
        int ix = (int)fx, iy = (int)fy, iz = (int)fz;
        float wx1 = cx - fx, wy1 = cy - fy, wz1 = cz - fz;
        int base = iz * PPLANE + iy * PPX + ix + CBASE;
        const float* q0 = padv + base;
        const float* q1 = q0 + PPLANE;
        const f2u p00 = *(const f2u*)q0;           // (v000, v001)
        const f2u p01 = *(const f2u*)(q0 + PPX);   // (v010, v011)
        const f2u p10 = *(const f2u*)q1;           // (v100, v101)
        const f2u p11 = *(const f2u*)(q1 + PPX);   // (v110, v111)
        float c00 = fmaf(wx1, p00.y - p00.x, p00.x);
        float c01 = fmaf(wx1, p01.y - p01.x, p01.x);
        float c10 = fmaf(wx1, p10.y - p10.x, p10.x);
        float c11 = fmaf(wx1, p11.y - p11.x, p11.x);
        float c0  = fmaf(wy1, c01 - c00, c00);
        float c1  = fmaf(wy1, c11 - c10, c10);
        acc += fmaf(wz1, c1 - c0, c0);
    }
    // two half-segments (2h, 2h+1) accumulate into slice h
    atomicAdd(&part[(hs >> 1) * NRAYS + r], acc);
}

// ------- residual + cw + Ram-Lak; writes TRANSPOSED resT[a][u][v] -------
__global__ __launch_bounds__(NU) void ramp_kernel(const float* __restrict__ part,
                                                  const float* __restrict__ p,
                                                  float* __restrict__ resT) {
    __shared__ float row[NU];
    int rowid = blockIdx.x;          // a*NV + v
    int u = threadIdx.x;
    int e = rowid * NU + u;
    int a = rowid >> 6;
    int v = rowid & (NV - 1);
    float sino = (part[e] + part[NRAYS + e] + part[2 * NRAYS + e] + part[3 * NRAYS + e]) * F_STEP;
    double du = (double)u - 64.0;
    double dv = (double)v - 32.0;
    float cw = (float)(512.0 / sqrt(262144.0 + dv * dv + du * du));
    row[u] = (sino - p[e]) * cw;
    __syncthreads();
    float acc = 0.125f * row[u];
#pragma unroll
    for (int d = 1; d <= 63; d += 2) {
        float f = (float)(-0.5 / (M_PI * M_PI * (double)(d * d)));
        float lo = (u - d >= 0) ? row[u - d] : 0.0f;
        float hi = (u + d < NU) ? row[u + d] : 0.0f;
        acc += f * (lo + hi);
    }
    resT[(a << 13) + (u << 6) + v] = acc;   // [a][u][v]
}

// ---------------- back projection: quarter-angle blocks (frozen, R10 best) ----------------
// bp ledger (R0-R10): generation-quantization CONFIRMED (12->6 pairs: -8%);
// 6->3 pairs: asymptote (305.6 vs 307). Per-PAIR wave-time conserved ~10us
// across all decompositions -> wall = wave-time/concurrency; perfect-packing
// floor ~253us. All other levers refuted: setup prefetch, occupancy trades,
// rotation, LDS k-loop, scramble, -21% VALU ops. bp frozen at R10's form.

#define SETUP_ANGLE(S, AIDX, AB)                                                 \
    const float c##S = CSA[AIDX], sn##S = SNA[AIDX];                             \
    const float c512##S = 512.0f * c##S;                                         \
    const float s512##S = 512.0f * sn##S;                                        \
    const float rho##S = fmaf(x0, c##S, fmaf(y0, sn##S, 256.0f));                \
    const float Vx##S = x0 + 256.0f * c##S;                                      \
    const float Vy##S = y0 + 256.0f * sn##S;                                     \
    const float tvlo##S = (rho##S - (AB)) * (1.0f / 512.0f);                     \
    const float yp##S = y0 * c##S - x0 * sn##S;                                  \
    const float rl##S = __builtin_amdgcn_rcpf(rho##S - (AB));                    \
    const float rh##S = __builtin_amdgcn_rcpf(rho##S + (AB));                    \
    const float A##S = yp##S - (AB), B##S = yp##S + (AB);                        \
    const float um##S = 512.0f * A##S * ((A##S >= 0.0f) ? rh##S : rl##S);        \
    const float uM##S = 512.0f * B##S * ((B##S >= 0.0f) ? rl##S : rh##S);        \
    const int u_lo##S = max(0,   (int)ceilf(um##S + 63.49f));                    \
    const int u_hi##S = min(127, (int)floorf(uM##S + 63.51f));                   \
    const int len##S = max(0, u_hi##S - u_lo##S + 1);                            \
    const float Zmin##S = fmaf(vvf, (vvf >= 0.0f) ? (tvlo##S - 1.0e-3f)          \
                                                  : (tvlo##S + 7.2e-3f), 31.5f); \
    const float izbf##S = floorf(Zmin##S);                                       \
    const int   izb##S  = (int)izbf##S;                                          \
    const float kzm1s##S = 30.5f - izbf##S;                                      \
    const v2f kzm1##S = {kzm1s##S, kzm1s##S};                                    \
    const float tDL##S = tvlo##S * INV_DL;                                       \
    const v2f mVx##S = {-Vx##S, -Vx##S}, mVy##S = {-Vy##S, -Vy##S};

#define BP_BODY2(S, RV, UU) do {                                                 \
    const float pu = fmaf(-(UU), sn##S, c512##S);                                \
    const float qu = fmaf((UU), c##S, s512##S);                                  \
    const float arg  = fmaf((UU), (UU), s2);                                     \
    const float invn = __builtin_amdgcn_rsqf(arg);                               \
    const float nn   = arg * invn;                                               \
    const float i0f  = ceilf(fmaf(tDL##S, nn, cK));                              \
    const float ell0 = fmaf(i0f, F_DL, F_L0);                                    \
    v2f tp; tp.x = ell0 * invn; tp.y = fmaf(F_DL, invn, tp.x);                   \
    const v2f pu2 = {pu, pu}, qu2 = {qu, qu};                                    \
    v2f wx = __builtin_elementwise_max(                                          \
        one2 - __builtin_elementwise_abs(__builtin_elementwise_fma(tp, pu2, mVx##S)), zero2); \
    v2f wy = __builtin_elementwise_max(                                          \
        one2 - __builtin_elementwise_abs(__builtin_elementwise_fma(tp, qu2, mVy##S)), zero2); \
    v2f val = wx * wy * (v2f){(RV), (RV)};                                       \
    const v2f t  = __builtin_elementwise_fma(tp, vv2, kzm1##S);                  \
    const v2f w1 = one2 - __builtin_elementwise_abs(t);   /* no clamp: |t|<=1 */ \
    const v2f w2 = __builtin_elementwise_max(t, zero2);                          \
    AC1##S = __builtin_elementwise_fma(w1, val, AC1##S);                         \
    AC2##S = __builtin_elementwise_fma(w2, val, AC2##S);                         \
    ACS##S = ACS##S + val;                                                       \
} while (0)

__global__ __launch_bounds__(256, 8) void bp_gather23(const float* __restrict__ resT,
                                                      float* __restrict__ out) {
    __shared__ float s_acc[4 * 64];       // per-wave z-accumulator columns

    const int tid  = threadIdx.x;
    const int lane = tid & 63;            // = v
    const int wv   = tid >> 6;            // wave 0..3

    const int bid  = blockIdx.x;          // 0..16383
    const int quarter = bid & 3;          // angle-pairs [3q .. 3q+2]
    const int y    = (bid >> 2) & 127;    // consecutive bids share (xq,y)
    const int xq   = bid >> 9;            // 0..31
    const int xi   = xq * 4 + wv;         // 4 consecutive x per block

    const float x0 = (float)xi - 63.5f;
    const float y0 = (float)y  - 63.5f;
    const float vvf = (float)lane - 31.5f;
    const float s2  = fmaf(vvf, vvf, 262144.0f);   // vv^2 + 512^2
    const v2f vv2   = {vvf, vvf};
    const v2f one2  = {1.0f, 1.0f}, zero2 = {0.0f, 0.0f};
    const float cK  = -(F_L0 * INV_DL) - 1.0e-3f;

    s_acc[tid] = 0.0f;

    const int pbase = quarter * 3;
    for (int jj = 0; jj < 3; ++jj) {
        const int pj = pbase + jj;        // wave-uniform (blockIdx-derived)
        const int a0 = 2 * pj, a1 = a0 + 1;
        const float ab1a = fabsf(CSA[a0]) + fabsf(SNA[a0]);
        const float ab1b = fabsf(CSA[a1]) + fabsf(SNA[a1]);

        SETUP_ANGLE(0, a0, ab1a);         // adjacent pair: lengths nearly equal
        SETUP_ANGLE(1, a1, ab1b);

        const int trips = (max(len0, len1) + 1) & ~1;   // round up to even
        if (trips == 0) continue;
        const int us0 = max(0, min(u_lo0, 128 - trips));
        const int us1 = max(0, min(u_lo1, 128 - trips));

        v2f ACS0 = zero2, AC10 = zero2, AC20 = zero2;
        v2f ACS1 = zero2, AC11 = zero2, AC21 = zero2;

        const float* ru0 = resT + (a0 << 13) + (us0 << 6) + lane;
        const float* ru1 = resT + (a1 << 13) + (us1 << 6) + lane;
        float uu0 = (float)us0 - 63.5f;
        float uu1 = (float)us1 - 63.5f;

        // 2-column prefetch pipeline; over-reads (<=3 cols past) stay inside ws
        float Ar0 = ru0[0],  Ar1 = ru1[0];
        float Br0 = ru0[64], Br1 = ru1[64];
#pragma unroll 1
        for (int k = 0; k < trips; k += 2) {
            const float Cr0 = ru0[128];
            const float Cr1 = ru1[128];
            const float Dr0 = ru0[192];
            const float Dr1 = ru1[192];
            BP_BODY2(0, Ar0, uu0);
            BP_BODY2(1, Ar1, uu1);
            BP_BODY2(0, Br0, uu0 + 1.0f);
            BP_BODY2(1, Br1, uu1 + 1.0f);
            Ar0 = Cr0; Ar1 = Cr1; Br0 = Dr0; Br1 = Dr1;
            ru0 += 128; ru1 += 128;
            uu0 += 2.0f; uu1 += 2.0f;
        }

        // AC0 reconstruction: w0+w1+w2 == 1 for g in [0,1.25] (exact in reals)
        const v2f r00 = ACS0 - AC10 - AC20;
        const v2f r01 = ACS1 - AC11 - AC21;

        float* accw = s_acc + (wv << 6);      // wave-private column
        atomicAdd(&accw[izb0],     r00.x + r00.y);
        atomicAdd(&accw[izb0 + 1], AC10.x + AC10.y);
        atomicAdd(&accw[izb0 + 2], AC20.x + AC20.y);
        atomicAdd(&accw[izb1],     r01.x + r01.y);
        atomicAdd(&accw[izb1 + 1], AC11.x + AC11.y);
        atomicAdd(&accw[izb1 + 2], AC21.x + AC21.y);
    }
    __syncthreads();

    // writeout: accumulate into out (4 quarter-blocks per voxel column)
    const int z  = tid >> 2;
    const int w4 = tid & 3;
    atomicAdd(&out[(z << 14) + (y << 7) + xq * 4 + w4],
              s_acc[(w4 << 6) + z] * F_STEP);
}

extern "C" void kernel_launch(void* const* d_in, const int* in_sizes, int n_in,
                              void* d_out, int out_size, void* d_ws, size_t ws_size,
                              hipStream_t stream) {
    const float* x = (const float*)d_in[0];   // [1,1,64,128,128]
    const float* p = (const float*)d_in[1];   // [1,1,24,64,128]
    float* out  = (float*)d_out;              // [1,1,64,128,128]
    float* resT = (float*)d_ws;               // transposed filtered residual, NRAYS floats
    float* part = resT + NRAYS;               // 4 FP slices, 4*NRAYS floats
    float* padv = part + NSEG * NRAYS;        // padded volume, PVN floats (~4.6 MB)

    pad_kernel<<<(PVN + 255) / 256, 256, 0, stream>>>(x, padv, out, part);
    dim3 fpg(NRAYS / 128, NHSEG);
    fp_seg_kernel<<<fpg, 128, 0, stream>>>(padv, part);
    ramp_kernel<<<NA * NV, NU, 0, stream>>>(part, p, resT);
    bp_gather23<<<128 * 32 * 4, 256, 0, stream>>>(resT, out);
}

// Round 13
// 413.121 us; speedup vs baseline: 1.0056x; 1.0056x over previous
//
#include <hip/hip_runtime.h>
#include <math.h>

// ---- geometry constants (match reference) ----
#define NA   24
#define NU   128
#define NV   64
#define NW   128   // volume W (x)
#define NH   128   // volume H (y)
#define ND   64    // volume D (z)
#define NS   128   // samples per ray
#define F_STEP 1.5625f            // 2*HS/S = 200/128
#define F_DL  (200.0f / 127.0f)   // linspace(156,356,128) spacing
#define F_L0  156.0f
#define INV_DL (127.0f / 200.0f)

#define NRAYS (NA * NV * NU)      // 196608
#define VOX   (NW * NH * ND)      // 1048576
#define NSEG  4

// padded volume: planes {guard, padz(-1), z0..z63, padz(64), guard} x 130 x 130
#define PPX  130
#define PPY  130
#define PPZ  68
#define PPLANE (PPX * PPY)        // 16900
#define PVN  (PPZ * PPLANE)       // 1,149,200
#define CBASE (2 * PPLANE + PPX + 1)   // voxel(0,0,0) linear offset

typedef float v2f __attribute__((ext_vector_type(2)));
// 8-byte vector load with only 4-byte alignment guarantee (per-lane x-pair).
typedef float f2v __attribute__((ext_vector_type(2)));
typedef f2v __attribute__((aligned(4))) f2u;

// cos/sin(k*15 deg)
__device__ __constant__ float CSA[NA] = {
    1.0f,  0.96592582628906829f,  0.86602540378443865f,  0.70710678118654752f,
    0.5f,  0.25881904510252076f,  0.0f,                 -0.25881904510252076f,
   -0.5f, -0.70710678118654752f, -0.86602540378443865f, -0.96592582628906829f,
   -1.0f, -0.96592582628906829f, -0.86602540378443865f, -0.70710678118654752f,
   -0.5f, -0.25881904510252076f,  0.0f,                  0.25881904510252076f,
    0.5f,  0.70710678118654752f,  0.86602540378443865f,  0.96592582628906829f
};
__device__ __constant__ float SNA[NA] = {
    0.0f,  0.25881904510252076f,  0.5f,                  0.70710678118654752f,
    0.86602540378443865f,  0.96592582628906829f,  1.0f,  0.96592582628906829f,
    0.86602540378443865f,  0.70710678118654752f,  0.5f,  0.25881904510252076f,
    0.0f, -0.25881904510252076f, -0.5f,                 -0.70710678118654752f,
   -0.86602540378443865f, -0.96592582628906829f, -1.0f, -0.96592582628906829f,
   -0.86602540378443865f, -0.70710678118654752f, -0.5f, -0.25881904510252076f
};

// ---------------- volume padding + out zero-init ----------------
// Zeroes `out` (bp accumulates via global atomicAdd from four quarter-blocks
// per voxel column). No part zeroing (R13: fp back to plain stores).
__global__ __launch_bounds__(256) void pad_kernel(const float* __restrict__ vol,
                                                  float* __restrict__ padv,
                                                  float* __restrict__ outz) {
    int i = blockIdx.x * 256 + threadIdx.x;
    if (i >= PVN) return;
    if (i < VOX) outz[i] = 0.0f;
    int x = i % PPX;
    int t = i / PPX;
    int y = t % PPY;
    int z = t / PPY;
    float val = 0.0f;
    if (z >= 2 && z <= 65 && y >= 1 && y <= 128 && x >= 1 && x <= 128)
        val = vol[(((z - 2) << 7) + (y - 1) << 7) + (x - 1)];
    padv[i] = val;
}

// Per-ray geometry for FP.
__device__ __forceinline__ void ray_setup(int a, int v, int u,
                                          float& sx, float& sy,
                                          float& dx, float& dy, float& dz) {
    float ang = (float)((double)a * (15.0 * M_PI / 180.0));
    float c = cosf(ang), s = sinf(ang);
    float uu = (float)u - 63.5f;
    float vv = (float)v - 31.5f;
    float ux = 512.0f * c - uu * s;
    float uy = 512.0f * s + uu * c;
    float uz = vv;
    float invn = 1.0f / sqrtf(ux * ux + uy * uy + uz * uz);
    dx = ux * invn; dy = uy * invn; dz = uz * invn;
    sx = -256.0f * c; sy = -256.0f * s;
}

// ---------------- forward projection, 4 ell-segments, padded-volume gather ----------------
// R13 (R28): UNBUNDLED quantization test. R12 bundled {128-thread blocks}
// (intended mechanism: fp was 3072 blocks / ~2048 slots = 1.5 ragged
// generations, worst case) with {16-sample atomics + part zeroing} (~8us
// fixed cost) and netted a regression. This round keeps ONLY the first:
// 128-thread blocks, same NSEG=4 x 32-sample segments, plain stores.
// Grid 6144 blocks = ~3 generations of half-size quanta. Arithmetic,
// store targets, and ramp sums are BIT-IDENTICAL to R10 -- only the
// block->ray mapping changes.
__global__ __launch_bounds__(128) void fp_seg_kernel(const float* __restrict__ padv,
                                                     float* __restrict__ part) {
    int r = blockIdx.x * 128 + threadIdx.x;
    int seg = blockIdx.y;
    int u = r & (NU - 1);
    int v = (r >> 7) & (NV - 1);
    int a = r >> 13;

    float sx, sy, dx, dy, dz;
    ray_setup(a, v, u, sx, sy, dx, dy, dz);

    // exact-support window (voxel weights are zero outside +-64.5 / +-32.5)
    float rx = 1.0f / dx, ry = 1.0f / dy, rz = 1.0f / dz;
    float ex0 = (-64.51f - sx) * rx, ex1 = (64.51f - sx) * rx;
    float ey0 = (-64.51f - sy) * ry, ey1 = (64.51f - sy) * ry;
    float ez0 = (-32.51f) * rz,      ez1 = (32.51f) * rz;
    float llo = fmaxf(fmaxf(fminf(ex0, ex1), fminf(ey0, ey1)), fminf(ez0, ez1));
    float lhi = fminf(fminf(fmaxf(ex0, ex1), fmaxf(ey0, ey1)), fmaxf(ez0, ez1));
    int i_lo = max(seg * 32,      (int)ceilf((llo - F_L0) * INV_DL));
    int i_hi = min(seg * 32 + 31, (int)floorf((lhi - F_L0) * INV_DL));

    float acc = 0.0f;
    for (int i = i_lo; i <= i_hi; ++i) {
        float ell = fmaf((float)i, F_DL, F_L0);
        float cx = fmaf(ell, dx, sx) + 63.5f;   // voxel-index space
        float cy = fmaf(ell, dy, sy) + 63.5f;
        float cz = ell * dz + 31.5f;
        float fx = floorf(cx), fy = floorf(cy), fz = floorf(cz);
        int ix = (int)fx, iy = (int)fy, iz = (int)fz;
        float wx1 = cx - fx, wy1 = cy - fy, wz1 = cz - fz;
        int base = iz * PPLANE + iy * PPX + ix + CBASE;
        const float* q0 = padv + base;
        const float* q1 = q0 + PPLANE;
        const f2u p00 = *(const f2u*)q0;           // (v000, v001)
        const f2u p01 = *(const f2u*)(q0 + PPX);   // (v010, v011)
        const f2u p10 = *(const f2u*)q1;           // (v100, v101)
        const f2u p11 = *(const f2u*)(q1 + PPX);   // (v110, v111)
        float c00 = fmaf(wx1, p00.y - p00.x, p00.x);
        float c01 = fmaf(wx1, p01.y - p01.x, p01.x);
        float c10 = fmaf(wx1, p10.y - p10.x, p10.x);
        float c11 = fmaf(wx1, p11.y - p11.x, p11.x);
        float c0  = fmaf(wy1, c01 - c00, c00);
        float c1  = fmaf(wy1, c11 - c10, c10);
        acc += fmaf(wz1, c1 - c0, c0);
    }
    part[seg * NRAYS + r] = acc;
}

// ------- residual + cw + Ram-Lak; writes TRANSPOSED resT[a][u][v] -------
__global__ __launch_bounds__(NU) void ramp_kernel(const float* __restrict__ part,
                                                  const float* __restrict__ p,
                                                  float* __restrict__ resT) {
    __shared__ float row[NU];
    int rowid = blockIdx.x;          // a*NV + v
    int u = threadIdx.x;
    int e = rowid * NU + u;
    int a = rowid >> 6;
    int v = rowid & (NV - 1);
    float sino = (part[e] + part[NRAYS + e] + part[2 * NRAYS + e] + part[3 * NRAYS + e]) * F_STEP;
    double du = (double)u - 64.0;
    double dv = (double)v - 32.0;
    float cw = (float)(512.0 / sqrt(262144.0 + dv * dv + du * du));
    row[u] = (sino - p[e]) * cw;
    __syncthreads();
    float acc = 0.125f * row[u];
#pragma unroll
    for (int d = 1; d <= 63; d += 2) {
        float f = (float)(-0.5 / (M_PI * M_PI * (double)(d * d)));
        float lo = (u - d >= 0) ? row[u - d] : 0.0f;
        float hi = (u + d < NU) ? row[u + d] : 0.0f;
        acc += f * (lo + hi);
    }
    resT[(a << 13) + (u << 6) + v] = acc;   // [a][u][v]
}

// ---------------- back projection: quarter-angle blocks (frozen, R10 best) ----------------
// bp ledger (R0-R12): generation-quantization CONFIRMED (12->6 pairs: -8%);
// 6->3 pairs: asymptote. Per-PAIR wave-time conserved ~10us across all
// decompositions -> wall = wave-time/concurrency; perfect-packing floor
// ~253us. Refuted: setup prefetch, occupancy trades, rotation, LDS k-loop,
// scramble, -21% VALU ops. 4-angle interleave analyzed and rejected
// (accumulator state ~70-80 VGPR -> occupancy loss eats the duty gain).
// bp frozen at R10's form.

#define SETUP_ANGLE(S, AIDX, AB)                                                 \
    const float c##S = CSA[AIDX], sn##S = SNA[AIDX];                             \
    const float c512##S = 512.0f * c##S;                                         \
    const float s512##S = 512.0f * sn##S;                                        \
    const float rho##S = fmaf(x0, c##S, fmaf(y0, sn##S, 256.0f));                \
    const float Vx##S = x0 + 256.0f * c##S;                                      \
    const float Vy##S = y0 + 256.0f * sn##S;                                     \
    const float tvlo##S = (rho##S - (AB)) * (1.0f / 512.0f);                     \
    const float yp##S = y0 * c##S - x0 * sn##S;                                  \
    const float rl##S = __builtin_amdgcn_rcpf(rho##S - (AB));                    \
    const float rh##S = __builtin_amdgcn_rcpf(rho##S + (AB));                    \
    const float A##S = yp##S - (AB), B##S = yp##S + (AB);                        \
    const float um##S = 512.0f * A##S * ((A##S >= 0.0f) ? rh##S : rl##S);        \
    const float uM##S = 512.0f * B##S * ((B##S >= 0.0f) ? rl##S : rh##S);        \
    const int u_lo##S = max(0,   (int)ceilf(um##S + 63.49f));                    \
    const int u_hi##S = min(127, (int)floorf(uM##S + 63.51f));                   \
    const int len##S = max(0, u_hi##S - u_lo##S + 1);                            \
    const float Zmin##S = fmaf(vvf, (vvf >= 0.0f) ? (tvlo##S - 1.0e-3f)          \
                                                  : (tvlo##S + 7.2e-3f), 31.5f); \
    const float izbf##S = floorf(Zmin##S);                                       \
    const int   izb##S  = (int)izbf##S;                                          \
    const float kzm1s##S = 30.5f - izbf##S;                                      \
    const v2f kzm1##S = {kzm1s##S, kzm1s##S};                                    \
    const float tDL##S = tvlo##S * INV_DL;                                       \
    const v2f mVx##S = {-Vx##S, -Vx##S}, mVy##S = {-Vy##S, -Vy##S};

#define BP_BODY2(S, RV, UU) do {                                                 \
    const float pu = fmaf(-(UU), sn##S, c512##S);                                \
    const float qu = fmaf((UU), c##S, s512##S);                                  \
    const float arg  = fmaf((UU), (UU), s2);                                     \
    const float invn = __builtin_amdgcn_rsqf(arg);                               \
    const float nn   = arg * invn;                                               \
    const float i0f  = ceilf(fmaf(tDL##S, nn, cK));                              \
    const float ell0 = fmaf(i0f, F_DL, F_L0);                                    \
    v2f tp; tp.x = ell0 * invn; tp.y = fmaf(F_DL, invn, tp.x);                   \
    const v2f pu2 = {pu, pu}, qu2 = {qu, qu};                                    \
    v2f wx = __builtin_elementwise_max(                                          \
        one2 - __builtin_elementwise_abs(__builtin_elementwise_fma(tp, pu2, mVx##S)), zero2); \
    v2f wy = __builtin_elementwise_max(                                          \
        one2 - __builtin_elementwise_abs(__builtin_elementwise_fma(tp, qu2, mVy##S)), zero2); \
    v2f val = wx * wy * (v2f){(RV), (RV)};                                       \
    const v2f t  = __builtin_elementwise_fma(tp, vv2, kzm1##S);                  \
    const v2f w1 = one2 - __builtin_elementwise_abs(t);   /* no clamp: |t|<=1 */ \
    const v2f w2 = __builtin_elementwise_max(t, zero2);                          \
    AC1##S = __builtin_elementwise_fma(w1, val, AC1##S);                         \
    AC2##S = __builtin_elementwise_fma(w2, val, AC2##S);                         \
    ACS##S = ACS##S + val;                                                       \
} while (0)

__global__ __launch_bounds__(256, 8) void bp_gather23(const float* __restrict__ resT,
                                                      float* __restrict__ out) {
    __shared__ float s_acc[4 * 64];       // per-wave z-accumulator columns

    const int tid  = threadIdx.x;
    const int lane = tid & 63;            // = v
    const int wv   = tid >> 6;            // wave 0..3

    const int bid  = blockIdx.x;          // 0..16383
    const int quarter = bid & 3;          // angle-pairs [3q .. 3q+2]
    const int y    = (bid >> 2) & 127;    // consecutive bids share (xq,y)
    const int xq   = bid >> 9;            // 0..31
    const int xi   = xq * 4 + wv;         // 4 consecutive x per block

    const float x0 = (float)xi - 63.5f;
    const float y0 = (float)y  - 63.5f;
    const float vvf = (float)lane - 31.5f;
    const float s2  = fmaf(vvf, vvf, 262144.0f);   // vv^2 + 512^2
    const v2f vv2   = {vvf, vvf};
    const v2f one2  = {1.0f, 1.0f}, zero2 = {0.0f, 0.0f};
    const float cK  = -(F_L0 * INV_DL) - 1.0e-3f;

    s_acc[tid] = 0.0f;

    const int pbase = quarter * 3;
    for (int jj = 0; jj < 3; ++jj) {
        const int pj = pbase + jj;        // wave-uniform (blockIdx-derived)
        const int a0 = 2 * pj, a1 = a0 + 1;
        const float ab1a = fabsf(CSA[a0]) + fabsf(SNA[a0]);
        const float ab1b = fabsf(CSA[a1]) + fabsf(SNA[a1]);

        SETUP_ANGLE(0, a0, ab1a);         // adjacent pair: lengths nearly equal
        SETUP_ANGLE(1, a1, ab1b);

        const int trips = (max(len0, len1) + 1) & ~1;   // round up to even
        if (trips == 0) continue;
        const int us0 = max(0, min(u_lo0, 128 - trips));
        const int us1 = max(0, min(u_lo1, 128 - trips));

        v2f ACS0 = zero2, AC10 = zero2, AC20 = zero2;
        v2f ACS1 = zero2, AC11 = zero2, AC21 = zero2;

        const float* ru0 = resT + (a0 << 13) + (us0 << 6) + lane;
        const float* ru1 = resT + (a1 << 13) + (us1 << 6) + lane;
        float uu0 = (float)us0 - 63.5f;
        float uu1 = (float)us1 - 63.5f;

        // 2-column prefetch pipeline; over-reads (<=3 cols past) stay inside ws
        float Ar0 = ru0[0],  Ar1 = ru1[0];
        float Br0 = ru0[64], Br1 = ru1[64];
#pragma unroll 1
        for (int k = 0; k < trips; k += 2) {
            const float Cr0 = ru0[128];
            const float Cr1 = ru1[128];
            const float Dr0 = ru0[192];
            const float Dr1 = ru1[192];
            BP_BODY2(0, Ar0, uu0);
            BP_BODY2(1, Ar1, uu1);
            BP_BODY2(0, Br0, uu0 + 1.0f);
            BP_BODY2(1, Br1, uu1 + 1.0f);
            Ar0 = Cr0; Ar1 = Cr1; Br0 = Dr0; Br1 = Dr1;
            ru0 += 128; ru1 += 128;
            uu0 += 2.0f; uu1 += 2.0f;
        }

        // AC0 reconstruction: w0+w1+w2 == 1 for g in [0,1.25] (exact in reals)
        const v2f r00 = ACS0 - AC10 - AC20;
        const v2f r01 = ACS1 - AC11 - AC21;

        float* accw = s_acc + (wv << 6);      // wave-private column
        atomicAdd(&accw[izb0],     r00.x + r00.y);
        atomicAdd(&accw[izb0 + 1], AC10.x + AC10.y);
        atomicAdd(&accw[izb0 + 2], AC20.x + AC20.y);
        atomicAdd(&accw[izb1],     r01.x + r01.y);
        atomicAdd(&accw[izb1 + 1], AC11.x + AC11.y);
        atomicAdd(&accw[izb1 + 2], AC21.x + AC21.y);
    }
    __syncthreads();

    // writeout: accumulate into out (4 quarter-blocks per voxel column)
    const int z  = tid >> 2;
    const int w4 = tid & 3;
    atomicAdd(&out[(z << 14) + (y << 7) + xq * 4 + w4],
              s_acc[(w4 << 6) + z] * F_STEP);
}

extern "C" void kernel_launch(void* const* d_in, const int* in_sizes, int n_in,
                              void* d_out, int out_size, void* d_ws, size_t ws_size,
                              hipStream_t stream) {
    const float* x = (const float*)d_in[0];   // [1,1,64,128,128]
    const float* p = (const float*)d_in[1];   // [1,1,24,64,128]
    float* out  = (float*)d_out;              // [1,1,64,128,128]
    float* resT = (float*)d_ws;               // transposed filtered residual, NRAYS floats
    float* part = resT + NRAYS;               // 4 FP segments, 4*NRAYS floats
    float* padv = part + NSEG * NRAYS;        // padded volume, PVN floats (~4.6 MB)

    pad_kernel<<<(PVN + 255) / 256, 256, 0, stream>>>(x, padv, out);
    dim3 fpg(NRAYS / 128, NSEG);
    fp_seg_kernel<<<fpg, 128, 0, stream>>>(padv, part);
    ramp_kernel<<<NA * NV, NU, 0, stream>>>(part, p, resT);
    bp_gather23<<<128 * 32 * 4, 256, 0, stream>>>(resT, out);
}

// Round 14
// 410.269 us; speedup vs baseline: 1.0126x; 1.0070x over previous
//
#include <hip/hip_runtime.h>
#include <math.h>

// ---- geometry constants (match reference) ----
#define NA   24
#define NU   128
#define NV   64
#define NW   128   // volume W (x)
#define NH   128   // volume H (y)
#define ND   64    // volume D (z)
#define NS   128   // samples per ray
#define F_STEP 1.5625f            // 2*HS/S = 200/128
#define F_DL  (200.0f / 127.0f)   // linspace(156,356,128) spacing
#define F_L0  156.0f
#define INV_DL (127.0f / 200.0f)

#define NRAYS (NA * NV * NU)      // 196608
#define VOX   (NW * NH * ND)      // 1048576
#define NSEG  4

// padded volume: planes {guard, padz(-1), z0..z63, padz(64), guard} x 130 x 130
#define PPX  130
#define PPY  130
#define PPZ  68
#define PPLANE (PPX * PPY)        // 16900
#define PVN  (PPZ * PPLANE)       // 1,149,200
#define CBASE (2 * PPLANE + PPX + 1)   // voxel(0,0,0) linear offset

typedef float v2f __attribute__((ext_vector_type(2)));
// 8-byte vector load with only 4-byte alignment guarantee (per-lane x-pair).
typedef float f2v __attribute__((ext_vector_type(2)));
typedef f2v __attribute__((aligned(4))) f2u;

// cos/sin(k*15 deg)
__device__ __constant__ float CSA[NA] = {
    1.0f,  0.96592582628906829f,  0.86602540378443865f,  0.70710678118654752f,
    0.5f,  0.25881904510252076f,  0.0f,                 -0.25881904510252076f,
   -0.5f, -0.70710678118654752f, -0.86602540378443865f, -0.96592582628906829f,
   -1.0f, -0.96592582628906829f, -0.86602540378443865f, -0.70710678118654752f,
   -0.5f, -0.25881904510252076f,  0.0f,                  0.25881904510252076f,
    0.5f,  0.70710678118654752f,  0.86602540378443865f,  0.96592582628906829f
};
__device__ __constant__ float SNA[NA] = {
    0.0f,  0.25881904510252076f,  0.5f,                  0.70710678118654752f,
    0.86602540378443865f,  0.96592582628906829f,  1.0f,  0.96592582628906829f,
    0.86602540378443865f,  0.70710678118654752f,  0.5f,  0.25881904510252076f,
    0.0f, -0.25881904510252076f, -0.5f,                 -0.70710678118654752f,
   -0.86602540378443865f, -0.96592582628906829f, -1.0f, -0.96592582628906829f,
   -0.86602540378443865f, -0.70710678118654752f, -0.5f, -0.25881904510252076f
};

// ---------------- volume padding + out zero-init ----------------
// Zeroes `out` (bp accumulates via global atomicAdd from four quarter-blocks
// per voxel column). Piggybacked here: no memset API inside graph capture;
// stream order pad -> ... -> bp guarantees visibility.
__global__ __launch_bounds__(256) void pad_kernel(const float* __restrict__ vol,
                                                  float* __restrict__ padv,
                                                  float* __restrict__ outz) {
    int i = blockIdx.x * 256 + threadIdx.x;
    if (i >= PVN) return;
    if (i < VOX) outz[i] = 0.0f;
    int x = i % PPX;
    int t = i / PPX;
    int y = t % PPY;
    int z = t / PPY;
    float val = 0.0f;
    if (z >= 2 && z <= 65 && y >= 1 && y <= 128 && x >= 1 && x <= 128)
        val = vol[(((z - 2) << 7) + (y - 1) << 7) + (x - 1)];
    padv[i] = val;
}

// Per-ray geometry for FP.
__device__ __forceinline__ void ray_setup(int a, int v, int u,
                                          float& sx, float& sy,
                                          float& dx, float& dy, float& dz) {
    float ang = (float)((double)a * (15.0 * M_PI / 180.0));
    float c = cosf(ang), s = sinf(ang);
    float uu = (float)u - 63.5f;
    float vv = (float)v - 31.5f;
    float ux = 512.0f * c - uu * s;
    float uy = 512.0f * s + uu * c;
    float uz = vv;
    float invn = 1.0f / sqrtf(ux * ux + uy * uy + uz * uz);
    dx = ux * invn; dy = uy * invn; dz = uz * invn;
    sx = -256.0f * c; sy = -256.0f * s;
}

// ---------------- forward projection, 4 ell-segments, padded-volume gather ----------------
// R14 final: exact R10 form (256-thread blocks, pair loads). fp ledger:
// pair-loads -2us (kept); unroll-2 +7us, rotating prefetch null, 128-thread
// quantum null, 16-sample atomics regression (all reverted). fp sits at the
// same L2-latency equilibrium as bp; no tested source-level lever moves it.
__global__ __launch_bounds__(256) void fp_seg_kernel(const float* __restrict__ padv,
                                                     float* __restrict__ part) {
    int r = blockIdx.x * blockDim.x + threadIdx.x;
    int seg = blockIdx.y;
    int u = r & (NU - 1);
    int v = (r >> 7) & (NV - 1);
    int a = r >> 13;

    float sx, sy, dx, dy, dz;
    ray_setup(a, v, u, sx, sy, dx, dy, dz);

    // exact-support window (voxel weights are zero outside +-64.5 / +-32.5)
    float rx = 1.0f / dx, ry = 1.0f / dy, rz = 1.0f / dz;
    float ex0 = (-64.51f - sx) * rx, ex1 = (64.51f - sx) * rx;
    float ey0 = (-64.51f - sy) * ry, ey1 = (64.51f - sy) * ry;
    float ez0 = (-32.51f) * rz,      ez1 = (32.51f) * rz;
    float llo = fmaxf(fmaxf(fminf(ex0, ex1), fminf(ey0, ey1)), fminf(ez0, ez1));
    float lhi = fminf(fminf(fmaxf(ex0, ex1), fmaxf(ey0, ey1)), fmaxf(ez0, ez1));
    int i_lo = max(seg * 32,      (int)ceilf((llo - F_L0) * INV_DL));
    int i_hi = min(seg * 32 + 31, (int)floorf((lhi - F_L0) * INV_DL));

    float acc = 0.0f;
    for (int i = i_lo; i <= i_hi; ++i) {
        float ell = fmaf((float)i, F_DL, F_L0);
        float cx = fmaf(ell, dx, sx) + 63.5f;   // voxel-index space
        float cy = fmaf(ell, dy, sy) + 63.5f;
        float cz = ell * dz + 31.5f;
        float fx = floorf(cx), fy = floorf(cy), fz = floorf(cz);
        int ix = (int)fx, iy = (int)fy, iz = (int)fz;
        float wx1 = cx - fx, wy1 = cy - fy, wz1 = cz - fz;
        int base = iz * PPLANE + iy * PPX + ix + CBASE;
        const float* q0 = padv + base;
        const float* q1 = q0 + PPLANE;
        const f2u p00 = *(const f2u*)q0;           // (v000, v001)
        const f2u p01 = *(const f2u*)(q0 + PPX);   // (v010, v011)
        const f2u p10 = *(const f2u*)q1;           // (v100, v101)
        const f2u p11 = *(const f2u*)(q1 + PPX);   // (v110, v111)
        float c00 = fmaf(wx1, p00.y - p00.x, p00.x);
        float c01 = fmaf(wx1, p01.y - p01.x, p01.x);
        float c10 = fmaf(wx1, p10.y - p10.x, p10.x);
        float c11 = fmaf(wx1, p11.y - p11.x, p11.x);
        float c0  = fmaf(wy1, c01 - c00, c00);
        float c1  = fmaf(wy1, c11 - c10, c10);
        acc += fmaf(wz1, c1 - c0, c0);
    }
    part[seg * NRAYS + r] = acc;
}

// ------- residual + cw + Ram-Lak; writes TRANSPOSED resT[a][u][v] -------
__global__ __launch_bounds__(NU) void ramp_kernel(const float* __restrict__ part,
                                                  const float* __restrict__ p,
                                                  float* __restrict__ resT) {
    __shared__ float row[NU];
    int rowid = blockIdx.x;          // a*NV + v
    int u = threadIdx.x;
    int e = rowid * NU + u;
    int a = rowid >> 6;
    int v = rowid & (NV - 1);
    float sino = (part[e] + part[NRAYS + e] + part[2 * NRAYS + e] + part[3 * NRAYS + e]) * F_STEP;
    double du = (double)u - 64.0;
    double dv = (double)v - 32.0;
    float cw = (float)(512.0 / sqrt(262144.0 + dv * dv + du * du));
    row[u] = (sino - p[e]) * cw;
    __syncthreads();
    float acc = 0.125f * row[u];
#pragma unroll
    for (int d = 1; d <= 63; d += 2) {
        float f = (float)(-0.5 / (M_PI * M_PI * (double)(d * d)));
        float lo = (u - d >= 0) ? row[u - d] : 0.0f;
        float hi = (u + d < NU) ? row[u + d] : 0.0f;
        acc += f * (lo + hi);
    }
    resT[(a << 13) + (u << 6) + v] = acc;   // [a][u][v]
}

// ---------------- back projection: quarter-angle blocks (frozen, session best) ----------------
// Final ledger (R0-R13): generation-quantization CONFIRMED (12->6 pairs: -8%,
// occupancy 71->84%); 6->3 pairs: asymptote. z-tent sum-identity op-cut -1.5%.
// Per-PAIR wave-time conserved ~10us across all decompositions -> wall =
// wave-time/concurrency; perfect-packing floor ~253us (unreached: residual is
// an L2-latency-under-load equilibrium that survived FULL memory-path
// replacement in R5). Refuted: setup prefetch x2, occupancy trades x3,
// rotation, LDS k-loop, scramble, -21% VALU ops, fp packing/MLP/ILP levers.
// Session: 431.3 -> 409.9us (-5%).

#define SETUP_ANGLE(S, AIDX, AB)                                                 \
    const float c##S = CSA[AIDX], sn##S = SNA[AIDX];                             \
    const float c512##S = 512.0f * c##S;                                         \
    const float s512##S = 512.0f * sn##S;                                        \
    const float rho##S = fmaf(x0, c##S, fmaf(y0, sn##S, 256.0f));                \
    const float Vx##S = x0 + 256.0f * c##S;                                      \
    const float Vy##S = y0 + 256.0f * sn##S;                                     \
    const float tvlo##S = (rho##S - (AB)) * (1.0f / 512.0f);                     \
    const float yp##S = y0 * c##S - x0 * sn##S;                                  \
    const float rl##S = __builtin_amdgcn_rcpf(rho##S - (AB));                    \
    const float rh##S = __builtin_amdgcn_rcpf(rho##S + (AB));                    \
    const float A##S = yp##S - (AB), B##S = yp##S + (AB);                        \
    const float um##S = 512.0f * A##S * ((A##S >= 0.0f) ? rh##S : rl##S);        \
    const float uM##S = 512.0f * B##S * ((B##S >= 0.0f) ? rl##S : rh##S);        \
    const int u_lo##S = max(0,   (int)ceilf(um##S + 63.49f));                    \
    const int u_hi##S = min(127, (int)floorf(uM##S + 63.51f));                   \
    const int len##S = max(0, u_hi##S - u_lo##S + 1);                            \
    const float Zmin##S = fmaf(vvf, (vvf >= 0.0f) ? (tvlo##S - 1.0e-3f)          \
                                                  : (tvlo##S + 7.2e-3f), 31.5f); \
    const float izbf##S = floorf(Zmin##S);                                       \
    const int   izb##S  = (int)izbf##S;                                          \
    const float kzm1s##S = 30.5f - izbf##S;                                      \
    const v2f kzm1##S = {kzm1s##S, kzm1s##S};                                    \
    const float tDL##S = tvlo##S * INV_DL;                                       \
    const v2f mVx##S = {-Vx##S, -Vx##S}, mVy##S = {-Vy##S, -Vy##S};

#define BP_BODY2(S, RV, UU) do {                                                 \
    const float pu = fmaf(-(UU), sn##S, c512##S);                                \
    const float qu = fmaf((UU), c##S, s512##S);                                  \
    const float arg  = fmaf((UU), (UU), s2);                                     \
    const float invn = __builtin_amdgcn_rsqf(arg);                               \
    const float nn   = arg * invn;                                               \
    const float i0f  = ceilf(fmaf(tDL##S, nn, cK));                              \
    const float ell0 = fmaf(i0f, F_DL, F_L0);                                    \
    v2f tp; tp.x = ell0 * invn; tp.y = fmaf(F_DL, invn, tp.x);                   \
    const v2f pu2 = {pu, pu}, qu2 = {qu, qu};                                    \
    v2f wx = __builtin_elementwise_max(                                          \
        one2 - __builtin_elementwise_abs(__builtin_elementwise_fma(tp, pu2, mVx##S)), zero2); \
    v2f wy = __builtin_elementwise_max(                                          \
        one2 - __builtin_elementwise_abs(__builtin_elementwise_fma(tp, qu2, mVy##S)), zero2); \
    v2f val = wx * wy * (v2f){(RV), (RV)};                                       \
    const v2f t  = __builtin_elementwise_fma(tp, vv2, kzm1##S);                  \
    const v2f w1 = one2 - __builtin_elementwise_abs(t);   /* no clamp: |t|<=1 */ \
    const v2f w2 = __builtin_elementwise_max(t, zero2);                          \
    AC1##S = __builtin_elementwise_fma(w1, val, AC1##S);                         \
    AC2##S = __builtin_elementwise_fma(w2, val, AC2##S);                         \
    ACS##S = ACS##S + val;                                                       \
} while (0)

__global__ __launch_bounds__(256, 8) void bp_gather23(const float* __restrict__ resT,
                                                      float* __restrict__ out) {
    __shared__ float s_acc[4 * 64];       // per-wave z-accumulator columns

    const int tid  = threadIdx.x;
    const int lane = tid & 63;            // = v
    const int wv   = tid >> 6;            // wave 0..3

    const int bid  = blockIdx.x;          // 0..16383
    const int quarter = bid & 3;          // angle-pairs [3q .. 3q+2]
    const int y    = (bid >> 2) & 127;    // consecutive bids share (xq,y)
    const int xq   = bid >> 9;            // 0..31
    const int xi   = xq * 4 + wv;         // 4 consecutive x per block

    const float x0 = (float)xi - 63.5f;
    const float y0 = (float)y  - 63.5f;
    const float vvf = (float)lane - 31.5f;
    const float s2  = fmaf(vvf, vvf, 262144.0f);   // vv^2 + 512^2
    const v2f vv2   = {vvf, vvf};
    const v2f one2  = {1.0f, 1.0f}, zero2 = {0.0f, 0.0f};
    const float cK  = -(F_L0 * INV_DL) - 1.0e-3f;

    s_acc[tid] = 0.0f;

    const int pbase = quarter * 3;
    for (int jj = 0; jj < 3; ++jj) {
        const int pj = pbase + jj;        // wave-uniform (blockIdx-derived)
        const int a0 = 2 * pj, a1 = a0 + 1;
        const float ab1a = fabsf(CSA[a0]) + fabsf(SNA[a0]);
        const float ab1b = fabsf(CSA[a1]) + fabsf(SNA[a1]);

        SETUP_ANGLE(0, a0, ab1a);         // adjacent pair: lengths nearly equal
        SETUP_ANGLE(1, a1, ab1b);

        const int trips = (max(len0, len1) + 1) & ~1;   // round up to even
        if (trips == 0) continue;
        const int us0 = max(0, min(u_lo0, 128 - trips));
        const int us1 = max(0, min(u_lo1, 128 - trips));

        v2f ACS0 = zero2, AC10 = zero2, AC20 = zero2;
        v2f ACS1 = zero2, AC11 = zero2, AC21 = zero2;

        const float* ru0 = resT + (a0 << 13) + (us0 << 6) + lane;
        const float* ru1 = resT + (a1 << 13) + (us1 << 6) + lane;
        float uu0 = (float)us0 - 63.5f;
        float uu1 = (float)us1 - 63.5f;

        // 2-column prefetch pipeline; over-reads (<=3 cols past) stay inside ws
        float Ar0 = ru0[0],  Ar1 = ru1[0];
        float Br0 = ru0[64], Br1 = ru1[64];
#pragma unroll 1
        for (int k = 0; k < trips; k += 2) {
            const float Cr0 = ru0[128];
            const float Cr1 = ru1[128];
            const float Dr0 = ru0[192];
            const float Dr1 = ru1[192];
            BP_BODY2(0, Ar0, uu0);
            BP_BODY2(1, Ar1, uu1);
            BP_BODY2(0, Br0, uu0 + 1.0f);
            BP_BODY2(1, Br1, uu1 + 1.0f);
            Ar0 = Cr0; Ar1 = Cr1; Br0 = Dr0; Br1 = Dr1;
            ru0 += 128; ru1 += 128;
            uu0 += 2.0f; uu1 += 2.0f;
        }

        // AC0 reconstruction: w0+w1+w2 == 1 for g in [0,1.25] (exact in reals)
        const v2f r00 = ACS0 - AC10 - AC20;
        const v2f r01 = ACS1 - AC11 - AC21;

        float* accw = s_acc + (wv << 6);      // wave-private column
        atomicAdd(&accw[izb0],     r00.x + r00.y);
        atomicAdd(&accw[izb0 + 1], AC10.x + AC10.y);
        atomicAdd(&accw[izb0 + 2], AC20.x + AC20.y);
        atomicAdd(&accw[izb1],     r01.x + r01.y);
        atomicAdd(&accw[izb1 + 1], AC11.x + AC11.y);
        atomicAdd(&accw[izb1 + 2], AC21.x + AC21.y);
    }
    __syncthreads();

    // writeout: accumulate into out (4 quarter-blocks per voxel column)
    const int z  = tid >> 2;
    const int w4 = tid & 3;
    atomicAdd(&out[(z << 14) + (y << 7) + xq * 4 + w4],
              s_acc[(w4 << 6) + z] * F_STEP);
}

extern "C" void kernel_launch(void* const* d_in, const int* in_sizes, int n_in,
                              void* d_out, int out_size, void* d_ws, size_t ws_size,
                              hipStream_t stream) {
    const float* x = (const float*)d_in[0];   // [1,1,64,128,128]
    const float* p = (const float*)d_in[1];   // [1,1,24,64,128]
    float* out  = (float*)d_out;              // [1,1,64,128,128]
    float* resT = (float*)d_ws;               // transposed filtered residual, NRAYS floats
    float* part = resT + NRAYS;               // 4 FP segments, 4*NRAYS floats
    float* padv = part + NSEG * NRAYS;        // padded volume, PVN floats (~4.6 MB)

    pad_kernel<<<(PVN + 255) / 256, 256, 0, stream>>>(x, padv, out);
    dim3 fpg(NRAYS / 256, NSEG);
    fp_seg_kernel<<<fpg, 256, 0, stream>>>(padv, part);
    ramp_kernel<<<NA * NV, NU, 0, stream>>>(part, p, resT);
    bp_gather23<<<128 * 32 * 4, 256, 0, stream>>>(resT, out);
}